// Round 1
// baseline (425.584 us; speedup 1.0000x reference)
//
#include <hip/hip_runtime.h>
#include <stdint.h>

typedef __bf16 bf16;
typedef __bf16 bf16x4 __attribute__((ext_vector_type(4)));
typedef __bf16 bf16x8 __attribute__((ext_vector_type(8)));
typedef float f32x4 __attribute__((ext_vector_type(4)));

#define CN 524288    // C*N = 512*1024 (per-batch x elements)
#define NPIX 1024
#define CCH 512

// ---- async global->LDS, 16B per lane (CK-style addrspace casts) ----
__device__ __forceinline__ void gload_lds16(const void* g, void* l) {
  auto gp = reinterpret_cast<const __attribute__((address_space(1))) uint32_t*>(
      reinterpret_cast<uintptr_t>(g));
  auto lp = reinterpret_cast<__attribute__((address_space(3))) uint32_t*>(
      static_cast<uint32_t>(reinterpret_cast<uintptr_t>(l)));
  __builtin_amdgcn_global_load_lds(gp, lp, 16, 0, 0);
}

// ======================================================================
// gemm_bt: C[i,j] = sum_k A[i,k] * Bt[j,k]   (m97 structure: 128x128 tile,
// BK=32, 4 waves each 64x64, global_load_lds staging, 16x16x32 bf16 MFMA)
// EPI 0: QKV   (bias add; j<1024 -> qkT[i][j], else v[j-1024][i])
// EPI 1: scores (fp32 out, * scale)
// EPI 2: PV    (bf16 out, ld=512)
// EPI 3: proj  (fp32 out + proj_b[i] + resid)
// ======================================================================
template<int EPI>
__global__ __launch_bounds__(256)
void gemm_bt(const bf16* __restrict__ A, int lda, long long sA,
             const bf16* __restrict__ Bt, int ldb, long long sB,
             char* __restrict__ Cp, long long sC,
             char* __restrict__ C2p, long long sC2,
             const float* __restrict__ bias,
             const float* __restrict__ resid,
             int K, float scale)
{
  __shared__ __align__(16) bf16 As[128 * 32];
  __shared__ __align__(16) bf16 Bs[128 * 32];
  const int t = threadIdx.x;
  const int w = t >> 6;
  const int l = t & 63;
  const int z = blockIdx.z;
  A  += (long long)z * sA;
  Bt += (long long)z * sB;
  Cp += (long long)z * sC;
  if (C2p) C2p += (long long)z * sC2;
  const float* residb = (EPI == 3) ? (resid + (long long)z * CN) : nullptr;

  const int row0 = blockIdx.x * 128;
  const int col0 = blockIdx.y * 128;
  const int wr = (w >> 1) * 64;
  const int wc = (w & 1) * 64;

  f32x4 acc[4][4] = {};

  const int r0 = t >> 2;              // staging: row within 64-row half
  const int s0 = t & 3;               // 16B segment within 64B row
  const int lrow = l & 15;
  const int kseg = (l >> 4) * 8;

  for (int k0 = 0; k0 < K; k0 += 32) {
    #pragma unroll
    for (int half = 0; half < 2; ++half) {
      const int r = half * 64 + r0;
      const bf16* ga = A  + (long long)(row0 + r) * lda + k0 + s0 * 8;
      const bf16* gb = Bt + (long long)(col0 + r) * ldb + k0 + s0 * 8;
      bf16* la = &As[(half * 256 + w * 64) * 8];   // wave-uniform LDS base
      bf16* lb = &Bs[(half * 256 + w * 64) * 8];
      gload_lds16(ga, la);
      gload_lds16(gb, lb);
    }
    __syncthreads();   // compiler drains vmcnt(0) before s_barrier
    bf16x8 af[4], bfr[4];
    #pragma unroll
    for (int m = 0; m < 4; ++m)
      af[m] = *(const bf16x8*)&As[(wr + m * 16 + lrow) * 32 + kseg];
    #pragma unroll
    for (int n = 0; n < 4; ++n)
      bfr[n] = *(const bf16x8*)&Bs[(wc + n * 16 + lrow) * 32 + kseg];
    #pragma unroll
    for (int m = 0; m < 4; ++m)
      #pragma unroll
      for (int n = 0; n < 4; ++n)
        acc[m][n] = __builtin_amdgcn_mfma_f32_16x16x32_bf16(af[m], bfr[n], acc[m][n], 0, 0, 0);
    __syncthreads();
  }

  (void)scale;
  const int ci = (l >> 4) * 4;
  const int cj = l & 15;
  #pragma unroll
  for (int m = 0; m < 4; ++m) {
    const int i0 = row0 + wr + m * 16 + ci;
    #pragma unroll
    for (int n = 0; n < 4; ++n) {
      const int j = col0 + wc + n * 16 + cj;
      const f32x4 a = acc[m][n];
      if constexpr (EPI == 0) {
        const float bj = bias[j];
        if (j < NPIX) {
          bf16* q = (bf16*)Cp;
          #pragma unroll
          for (int r = 0; r < 4; ++r)
            q[(i0 + r) * NPIX + j] = (bf16)(a[r] + bj);
        } else {
          bf16* vb = (bf16*)C2p;
          #pragma unroll
          for (int r = 0; r < 4; ++r)
            vb[(j - NPIX) * NPIX + (i0 + r)] = (bf16)(a[r] + bj);
        }
      } else if constexpr (EPI == 1) {
        float* sp = (float*)Cp;
        #pragma unroll
        for (int r = 0; r < 4; ++r)
          sp[(i0 + r) * NPIX + j] = a[r] * scale;
      } else if constexpr (EPI == 2) {
        bf16* hp = (bf16*)Cp;
        #pragma unroll
        for (int r = 0; r < 4; ++r)
          hp[(i0 + r) * CCH + j] = (bf16)a[r];
      } else {
        float* op = (float*)Cp;
        #pragma unroll
        for (int r = 0; r < 4; ++r)
          op[(i0 + r) * NPIX + j] = a[r] + bias[i0 + r] + residb[(i0 + r) * NPIX + j];
      }
    }
  }
}

// ---- GroupNorm stats: one block per (batch,group), 16ch x 1024 px ----
__global__ __launch_bounds__(256)
void gn_stats(const float* __restrict__ x, float2* __restrict__ stats)
{
  const int bg = blockIdx.x;
  const float4* p = (const float4*)(x + (long long)bg * 16384);
  const int t = threadIdx.x;
  float s = 0.f, ss = 0.f;
  for (int i = t; i < 4096; i += 256) {
    float4 v = p[i];
    s  += v.x + v.y + v.z + v.w;
    ss += v.x * v.x + v.y * v.y + v.z * v.z + v.w * v.w;
  }
  #pragma unroll
  for (int o = 32; o; o >>= 1) { s += __shfl_xor(s, o); ss += __shfl_xor(ss, o); }
  __shared__ float red[8];
  if ((t & 63) == 0) { red[t >> 6] = s; red[4 + (t >> 6)] = ss; }
  __syncthreads();
  if (t == 0) {
    s  = red[0] + red[1] + red[2] + red[3];
    ss = red[4] + red[5] + red[6] + red[7];
    const float mean = s * (1.f / 16384.f);
    const float var  = ss * (1.f / 16384.f) - mean * mean;
    stats[bg] = make_float2(mean, 1.f / sqrtf(var + 1e-5f));
  }
}

// ---- normalize + transpose: x[b][c][n] -> hnT[b][n][c] (bf16) ----
__global__ __launch_bounds__(256)
void gn_apply_t(const float* __restrict__ x, const float2* __restrict__ stats,
                const float* __restrict__ gw, const float* __restrict__ gb,
                bf16* __restrict__ hnT)
{
  __shared__ float tile[32][33];
  const int b = blockIdx.z;
  const int n0 = blockIdx.x * 32;
  const int c0 = blockIdx.y * 32;
  const int tx = threadIdx.x, ty = threadIdx.y;
  const float* xb = x + (long long)b * CN;
  #pragma unroll
  for (int r = 0; r < 32; r += 8) {
    const int c = c0 + ty + r;
    const float2 st = stats[b * 32 + (c >> 4)];
    const float v = xb[(long long)c * NPIX + n0 + tx];
    tile[ty + r][tx] = (v - st.x) * st.y * gw[c] + gb[c];
  }
  __syncthreads();
  bf16* hb = hnT + (long long)b * CN;
  #pragma unroll
  for (int r = 0; r < 32; r += 8) {
    const int n = n0 + ty + r;
    hb[(long long)n * CCH + c0 + tx] = (bf16)tile[tx][ty + r];
  }
}

// ---- row softmax over 1024 fp32, write bf16 IN PLACE (row stride 4KB) ----
__global__ __launch_bounds__(256)
void softmax_rows(float* __restrict__ scores)
{
  float* p = scores + (long long)blockIdx.x * NPIX;
  const int t = threadIdx.x;
  const float4 v = ((const float4*)p)[t];
  float m = fmaxf(fmaxf(v.x, v.y), fmaxf(v.z, v.w));
  #pragma unroll
  for (int o = 32; o; o >>= 1) m = fmaxf(m, __shfl_xor(m, o));
  __shared__ float red[4];
  if ((t & 63) == 0) red[t >> 6] = m;
  __syncthreads();
  m = fmaxf(fmaxf(red[0], red[1]), fmaxf(red[2], red[3]));
  float4 e;
  e.x = __expf(v.x - m); e.y = __expf(v.y - m);
  e.z = __expf(v.z - m); e.w = __expf(v.w - m);
  float s = e.x + e.y + e.z + e.w;
  #pragma unroll
  for (int o = 32; o; o >>= 1) s += __shfl_xor(s, o);
  __syncthreads();                     // red reuse + all reads complete
  if ((t & 63) == 0) red[t >> 6] = s;
  __syncthreads();
  s = red[0] + red[1] + red[2] + red[3];
  const float inv = 1.f / s;
  bf16x4 ov;
  ov[0] = (bf16)(e.x * inv); ov[1] = (bf16)(e.y * inv);
  ov[2] = (bf16)(e.z * inv); ov[3] = (bf16)(e.w * inv);
  *(bf16x4*)((bf16*)p + t * 4) = ov;
}

// ---- fp32 -> bf16 weight conversion (once) ----
__global__ __launch_bounds__(256)
void cvt_weights(const float* __restrict__ qw, const float* __restrict__ pw,
                 bf16* __restrict__ qwb, bf16* __restrict__ pwb)
{
  const int i = blockIdx.x * 256 + threadIdx.x;
  if (i < 3 * CCH * CCH) qwb[i] = (bf16)qw[i];
  if (i < CCH * CCH) pwb[i] = (bf16)pw[i];
}

extern "C" void kernel_launch(void* const* d_in, const int* in_sizes, int n_in,
                              void* d_out, int out_size, void* d_ws, size_t ws_size,
                              hipStream_t stream)
{
  const float* x      = (const float*)d_in[0];
  const float* gn_w   = (const float*)d_in[1];
  const float* gn_b   = (const float*)d_in[2];
  const float* qkv_w  = (const float*)d_in[3];
  const float* qkv_b  = (const float*)d_in[4];
  const float* proj_w = (const float*)d_in[5];
  const float* proj_b = (const float*)d_in[6];
  float* out = (float*)d_out;
  (void)in_sizes; (void)n_in; (void)out_size;

  char* ws = (char*)d_ws;
  size_t off = 0;
  auto alloc = [&](size_t bytes) -> char* {
    char* p = ws + off;
    off += (bytes + 255) & ~(size_t)255;
    return p;
  };
  bf16* qkv_wb  = (bf16*)alloc(3 * 512 * 512 * 2);
  bf16* proj_wb = (bf16*)alloc(512 * 512 * 2);
  float2* stats = (float2*)alloc(1024 * sizeof(float2));
  const size_t fixed = off;
  // per-batch: hnT 1MB + qkT 2MB + v 1MB + scores 4MB + hvT 1MB
  const size_t per = 1048576ull + 2097152ull + 1048576ull + 4194304ull + 1048576ull;
  int Bc = 32;
  if (ws_size > fixed) {
    size_t fit = (ws_size - fixed) / per;
    if (fit < 32) Bc = (int)fit;
  } else {
    Bc = 0;
  }
  if (Bc < 1) Bc = 1;

  bf16*  hnT    = (bf16*) alloc((size_t)Bc * 1048576);
  bf16*  qkT    = (bf16*) alloc((size_t)Bc * 2097152);
  bf16*  vbuf   = (bf16*) alloc((size_t)Bc * 1048576);
  float* scores = (float*)alloc((size_t)Bc * 4194304);
  bf16*  hvT    = (bf16*) alloc((size_t)Bc * 1048576);

  cvt_weights<<<dim3(3072), 256, 0, stream>>>(qkv_w, proj_w, qkv_wb, proj_wb);

  const float scale = 0.044194173824159216f;  // 512^-0.5
  for (int b0 = 0; b0 < 32; b0 += Bc) {
    const int bc = (32 - b0 < Bc) ? (32 - b0) : Bc;
    const float* xb = x + (size_t)b0 * CN;

    gn_stats<<<dim3(bc * 32), 256, 0, stream>>>(xb, stats);
    gn_apply_t<<<dim3(32, 16, bc), dim3(32, 8), 0, stream>>>(xb, stats, gn_w, gn_b, hnT);

    // QKV: [n][o] = hnT[n][c] . qkv_w[o][c];  q,k -> qkT[n][0..1023], v -> vbuf[c][m]
    gemm_bt<0><<<dim3(8, 12, bc), 256, 0, stream>>>(
        hnT, 512, 524288, qkv_wb, 512, 0,
        (char*)qkT, 2097152, (char*)vbuf, 1048576, qkv_b, nullptr, 512, 1.f);

    // scores[n][m] = q[n][:] . k[m][:]  (fp32, *scale)
    gemm_bt<1><<<dim3(8, 8, bc), 256, 0, stream>>>(
        qkT, 1024, 1048576, qkT + 512, 1024, 1048576,
        (char*)scores, 4194304, nullptr, 0, nullptr, nullptr, 512, scale);

    softmax_rows<<<dim3(bc * 1024), 256, 0, stream>>>(scores);

    // hvT[n][c] = attn[n][m] . v[c][m]   (attn bf16 in-place, lda=2048 elems)
    gemm_bt<2><<<dim3(8, 4, bc), 256, 0, stream>>>(
        (const bf16*)scores, 2048, 2097152, vbuf, 1024, 524288,
        (char*)hvT, 1048576, nullptr, 0, nullptr, nullptr, 1024, 1.f);

    // out[c][n] = proj_w[c][:] . hvT[n][:] + proj_b[c] + x[c][n]
    gemm_bt<3><<<dim3(4, 8, bc), 256, 0, stream>>>(
        proj_wb, 512, 0, hvT, 512, 524288,
        (char*)(out + (size_t)b0 * CN), 2097152, nullptr, 0, proj_b, xb, 512, 1.f);
  }
}

// Round 2
// 374.117 us; speedup vs baseline: 1.1376x; 1.1376x over previous
//
#include <hip/hip_runtime.h>
#include <stdint.h>

typedef __bf16 bf16;
typedef __bf16 bf16x4 __attribute__((ext_vector_type(4)));
typedef __bf16 bf16x8 __attribute__((ext_vector_type(8)));
typedef float f32x4 __attribute__((ext_vector_type(4)));

#define CN 524288    // C*N = 512*1024 (per-batch x elements)
#define NPIX 1024
#define CCH 512

// ---- async global->LDS, 16B per lane ----
__device__ __forceinline__ void gload_lds16(const void* g, void* l) {
  auto gp = reinterpret_cast<const __attribute__((address_space(1))) uint32_t*>(
      reinterpret_cast<uintptr_t>(g));
  auto lp = reinterpret_cast<__attribute__((address_space(3))) uint32_t*>(
      static_cast<uint32_t>(reinterpret_cast<uintptr_t>(l)));
  __builtin_amdgcn_global_load_lds(gp, lp, 16, 0, 0);
}

// ======================================================================
// gemm_bt: C[i,j] = sum_k A[i,k] * Bt[j,k]
// 128x128 tile, BK=64, 4 waves (64x64 each), 16x16x32 bf16 MFMA.
// LDS linear [128][64]; XOR swizzle (seg ^= row&7, 16B segs of the 128B row)
// applied on the pre-swizzled GLOBAL source and on the ds_read address
// (both-sides involution) -> conflict-free ds_read_b128.
// EPI 0: QKV   (bias; j<1024 -> qkT[i][j], else v[j-1024][i])
// EPI 1: scores (fp32 out, * scale)
// EPI 2: PV    (bf16 out, ld=512)
// EPI 3: proj  (fp32 out + proj_b[i] + resid)
// ======================================================================
template<int EPI>
__global__ __launch_bounds__(256)
void gemm_bt(const bf16* __restrict__ A, int lda, long long sA,
             const bf16* __restrict__ Bt, int ldb, long long sB,
             char* __restrict__ Cp, long long sC,
             char* __restrict__ C2p, long long sC2,
             const float* __restrict__ bias,
             const float* __restrict__ resid,
             int K, float scale)
{
  __shared__ __align__(16) bf16 As[128 * 64];
  __shared__ __align__(16) bf16 Bs[128 * 64];
  const int t = threadIdx.x;
  const int w = t >> 6;
  const int l = t & 63;
  const int z = blockIdx.z;
  A  += (long long)z * sA;
  Bt += (long long)z * sB;
  Cp += (long long)z * sC;
  if (C2p) C2p += (long long)z * sC2;
  const float* residb = (EPI == 3) ? (resid + (long long)z * CN) : nullptr;

  const int row0 = blockIdx.x * 128;
  const int col0 = blockIdx.y * 128;
  const int wr = (w >> 1) * 64;
  const int wc = (w & 1) * 64;

  f32x4 acc[4][4] = {};

  const int srow = t >> 3;            // 0..31: row within 32-row staging chunk
  const int sseg = l & 7;             // 16B segment within 128B row (pre-swizzle)
  const int lrow = l & 15;
  const int lseg = l >> 4;            // 0..3

  for (int k0 = 0; k0 < K; k0 += 64) {
    #pragma unroll
    for (int li = 0; li < 4; ++li) {
      const int row = li * 32 + srow;
      const int kofs = k0 + ((sseg ^ (row & 7)) << 3);
      const bf16* ga = A  + (long long)(row0 + row) * lda + kofs;
      const bf16* gb = Bt + (long long)(col0 + row) * ldb + kofs;
      gload_lds16(ga, &As[li * 2048 + w * 512]);   // wave-uniform LDS base
      gload_lds16(gb, &Bs[li * 2048 + w * 512]);
    }
    __syncthreads();   // compiler drains vmcnt(0) before s_barrier
    #pragma unroll
    for (int kk = 0; kk < 2; ++kk) {
      bf16x8 af[4], bfr[4];
      #pragma unroll
      for (int m = 0; m < 4; ++m) {
        const int r = wr + m * 16 + lrow;
        const int sg = ((kk * 4 + lseg) ^ (r & 7)) * 8;
        af[m] = *(const bf16x8*)&As[r * 64 + sg];
      }
      #pragma unroll
      for (int n = 0; n < 4; ++n) {
        const int r = wc + n * 16 + lrow;
        const int sg = ((kk * 4 + lseg) ^ (r & 7)) * 8;
        bfr[n] = *(const bf16x8*)&Bs[r * 64 + sg];
      }
      #pragma unroll
      for (int m = 0; m < 4; ++m)
        #pragma unroll
        for (int n = 0; n < 4; ++n)
          acc[m][n] = __builtin_amdgcn_mfma_f32_16x16x32_bf16(af[m], bfr[n], acc[m][n], 0, 0, 0);
    }
    __syncthreads();
  }

  (void)scale;
  const int ci = (l >> 4) * 4;
  const int cj = l & 15;
  #pragma unroll
  for (int m = 0; m < 4; ++m) {
    const int i0 = row0 + wr + m * 16 + ci;
    #pragma unroll
    for (int n = 0; n < 4; ++n) {
      const int j = col0 + wc + n * 16 + cj;
      const f32x4 a = acc[m][n];
      if constexpr (EPI == 0) {
        const float bj = bias[j];
        if (j < NPIX) {
          bf16* q = (bf16*)Cp;
          #pragma unroll
          for (int r = 0; r < 4; ++r)
            q[(i0 + r) * NPIX + j] = (bf16)(a[r] + bj);
        } else {
          bf16* vb = (bf16*)C2p;
          #pragma unroll
          for (int r = 0; r < 4; ++r)
            vb[(j - NPIX) * NPIX + (i0 + r)] = (bf16)(a[r] + bj);
        }
      } else if constexpr (EPI == 1) {
        float* sp = (float*)Cp;
        #pragma unroll
        for (int r = 0; r < 4; ++r)
          sp[(i0 + r) * NPIX + j] = a[r] * scale;
      } else if constexpr (EPI == 2) {
        bf16* hp = (bf16*)Cp;
        #pragma unroll
        for (int r = 0; r < 4; ++r)
          hp[(i0 + r) * CCH + j] = (bf16)a[r];
      } else {
        float* op = (float*)Cp;
        #pragma unroll
        for (int r = 0; r < 4; ++r)
          op[(i0 + r) * NPIX + j] = a[r] + bias[i0 + r] + residb[(i0 + r) * NPIX + j];
      }
    }
  }
}

// ---- fused GroupNorm: one block per (batch,group); 16ch x 1024px in LDS,
//      stats + normalize + transpose-write hnT[n][c] (bf16) in one pass ----
__global__ __launch_bounds__(256)
void gn_fused(const float* __restrict__ x, const float* __restrict__ gw,
              const float* __restrict__ gb, bf16* __restrict__ hnT)
{
  __shared__ float xs[16 * 1024];   // 64 KB
  __shared__ float red[8];
  const int b = blockIdx.x >> 5;
  const int g = blockIdx.x & 31;
  const float* xp = x + ((long long)b * CCH + g * 16) * NPIX;
  const int t = threadIdx.x;

  float4* xsv = (float4*)xs;
  const float4* gv = (const float4*)xp;
  float s = 0.f, ss = 0.f;
  #pragma unroll
  for (int i = 0; i < 16; ++i) {
    float4 v = gv[t + i * 256];
    xsv[t + i * 256] = v;
    s  += v.x + v.y + v.z + v.w;
    ss += v.x * v.x + v.y * v.y + v.z * v.z + v.w * v.w;
  }
  #pragma unroll
  for (int o = 32; o; o >>= 1) { s += __shfl_xor(s, o); ss += __shfl_xor(ss, o); }
  if ((t & 63) == 0) { red[t >> 6] = s; red[4 + (t >> 6)] = ss; }
  __syncthreads();
  s  = red[0] + red[1] + red[2] + red[3];
  ss = red[4] + red[5] + red[6] + red[7];
  const float mean = s * (1.f / 16384.f);
  const float var  = ss * (1.f / 16384.f) - mean * mean;
  const float rstd = rsqrtf(var + 1e-5f);

  float ac[16], bc[16];
  #pragma unroll
  for (int c = 0; c < 16; ++c) {
    const float wv = gw[g * 16 + c] * rstd;
    ac[c] = wv;
    bc[c] = gb[g * 16 + c] - mean * wv;
  }

  bf16* hp = hnT + (long long)b * CN + g * 16;
  #pragma unroll
  for (int r = 0; r < 4; ++r) {
    const int n = t + r * 256;
    bf16x8 o0, o1;
    #pragma unroll
    for (int c = 0; c < 8; ++c)
      o0[c] = (bf16)(xs[c * 1024 + n] * ac[c] + bc[c]);
    #pragma unroll
    for (int c = 0; c < 8; ++c)
      o1[c] = (bf16)(xs[(8 + c) * 1024 + n] * ac[8 + c] + bc[8 + c]);
    *(bf16x8*)&hp[(long long)n * CCH]     = o0;
    *(bf16x8*)&hp[(long long)n * CCH + 8] = o1;
  }
}

// ---- row softmax over 1024 fp32, write bf16 IN PLACE (row stride 4KB) ----
__global__ __launch_bounds__(256)
void softmax_rows(float* __restrict__ scores)
{
  float* p = scores + (long long)blockIdx.x * NPIX;
  const int t = threadIdx.x;
  const float4 v = ((const float4*)p)[t];
  float m = fmaxf(fmaxf(v.x, v.y), fmaxf(v.z, v.w));
  #pragma unroll
  for (int o = 32; o; o >>= 1) m = fmaxf(m, __shfl_xor(m, o));
  __shared__ float red[4];
  if ((t & 63) == 0) red[t >> 6] = m;
  __syncthreads();
  m = fmaxf(fmaxf(red[0], red[1]), fmaxf(red[2], red[3]));
  float4 e;
  e.x = __expf(v.x - m); e.y = __expf(v.y - m);
  e.z = __expf(v.z - m); e.w = __expf(v.w - m);
  float s = e.x + e.y + e.z + e.w;
  #pragma unroll
  for (int o = 32; o; o >>= 1) s += __shfl_xor(s, o);
  __syncthreads();
  if ((t & 63) == 0) red[t >> 6] = s;
  __syncthreads();
  s = red[0] + red[1] + red[2] + red[3];
  const float inv = 1.f / s;
  bf16x4 ov;
  ov[0] = (bf16)(e.x * inv); ov[1] = (bf16)(e.y * inv);
  ov[2] = (bf16)(e.z * inv); ov[3] = (bf16)(e.w * inv);
  *(bf16x4*)((bf16*)p + t * 4) = ov;
}

// ---- fp32 -> bf16 weight conversion (once) ----
__global__ __launch_bounds__(256)
void cvt_weights(const float* __restrict__ qw, const float* __restrict__ pw,
                 bf16* __restrict__ qwb, bf16* __restrict__ pwb)
{
  const int i = blockIdx.x * 256 + threadIdx.x;
  if (i < 3 * CCH * CCH) qwb[i] = (bf16)qw[i];
  if (i < CCH * CCH) pwb[i] = (bf16)pw[i];
}

extern "C" void kernel_launch(void* const* d_in, const int* in_sizes, int n_in,
                              void* d_out, int out_size, void* d_ws, size_t ws_size,
                              hipStream_t stream)
{
  const float* x      = (const float*)d_in[0];
  const float* gn_w   = (const float*)d_in[1];
  const float* gn_b   = (const float*)d_in[2];
  const float* qkv_w  = (const float*)d_in[3];
  const float* qkv_b  = (const float*)d_in[4];
  const float* proj_w = (const float*)d_in[5];
  const float* proj_b = (const float*)d_in[6];
  float* out = (float*)d_out;
  (void)in_sizes; (void)n_in; (void)out_size;

  char* ws = (char*)d_ws;
  size_t off = 0;
  auto alloc = [&](size_t bytes) -> char* {
    char* p = ws + off;
    off += (bytes + 255) & ~(size_t)255;
    return p;
  };
  bf16* qkv_wb  = (bf16*)alloc(3 * 512 * 512 * 2);
  bf16* proj_wb = (bf16*)alloc(512 * 512 * 2);
  const size_t fixed = off;
  // per-batch: hnT 1MB + qkT 2MB + v 1MB + scores 4MB + hvT 1MB
  const size_t per = 1048576ull + 2097152ull + 1048576ull + 4194304ull + 1048576ull;
  int Bc = 32;
  if (ws_size > fixed) {
    size_t fit = (ws_size - fixed) / per;
    if (fit < 32) Bc = (int)fit;
  } else {
    Bc = 0;
  }
  if (Bc < 1) Bc = 1;

  bf16*  hnT    = (bf16*) alloc((size_t)Bc * 1048576);
  bf16*  qkT    = (bf16*) alloc((size_t)Bc * 2097152);
  bf16*  vbuf   = (bf16*) alloc((size_t)Bc * 1048576);
  float* scores = (float*)alloc((size_t)Bc * 4194304);
  bf16*  hvT    = (bf16*) alloc((size_t)Bc * 1048576);

  cvt_weights<<<dim3(3072), 256, 0, stream>>>(qkv_w, proj_w, qkv_wb, proj_wb);

  const float scale = 0.044194173824159216f;  // 512^-0.5
  for (int b0 = 0; b0 < 32; b0 += Bc) {
    const int bc = (32 - b0 < Bc) ? (32 - b0) : Bc;
    const float* xb = x + (size_t)b0 * CN;

    gn_fused<<<dim3(bc * 32), 256, 0, stream>>>(xb, gn_w, gn_b, hnT);

    // QKV: [n][o] = hnT[n][c] . qkv_w[o][c];  q,k -> qkT[n][0..1023], v -> vbuf[c][m]
    gemm_bt<0><<<dim3(8, 12, bc), 256, 0, stream>>>(
        hnT, 512, 524288, qkv_wb, 512, 0,
        (char*)qkT, 2097152, (char*)vbuf, 1048576, qkv_b, nullptr, 512, 1.f);

    // scores[n][m] = q[n][:] . k[m][:]  (fp32, *scale)
    gemm_bt<1><<<dim3(8, 8, bc), 256, 0, stream>>>(
        qkT, 1024, 1048576, qkT + 512, 1024, 1048576,
        (char*)scores, 4194304, nullptr, 0, nullptr, nullptr, 512, scale);

    softmax_rows<<<dim3(bc * 1024), 256, 0, stream>>>(scores);

    // hvT[n][c] = attn[n][m] . v[c][m]   (attn bf16 in-place, lda=2048 elems)
    gemm_bt<2><<<dim3(8, 4, bc), 256, 0, stream>>>(
        (const bf16*)scores, 2048, 2097152, vbuf, 1024, 524288,
        (char*)hvT, 1048576, nullptr, 0, nullptr, nullptr, 1024, 1.f);

    // out[c][n] = proj_w[c][:] . hvT[n][:] + proj_b[c] + x[c][n]
    gemm_bt<3><<<dim3(4, 8, bc), 256, 0, stream>>>(
        proj_wb, 512, 0, hvT, 512, 524288,
        (char*)(out + (size_t)b0 * CN), 2097152, nullptr, 0, proj_b, xb, 512, 1.f);
  }
}

// Round 3
// 357.511 us; speedup vs baseline: 1.1904x; 1.0464x over previous
//
#include <hip/hip_runtime.h>
#include <stdint.h>

typedef __bf16 bf16;
typedef __bf16 bf16x4 __attribute__((ext_vector_type(4)));
typedef __bf16 bf16x8 __attribute__((ext_vector_type(8)));
typedef float f32x4 __attribute__((ext_vector_type(4)));

#define CN 524288    // C*N = 512*1024 (per-batch x elements)
#define NPIX 1024
#define CCH 512

// ---- async global->LDS, 16B per lane ----
__device__ __forceinline__ void gload_lds16(const void* g, void* l) {
  auto gp = reinterpret_cast<const __attribute__((address_space(1))) uint32_t*>(
      reinterpret_cast<uintptr_t>(g));
  auto lp = reinterpret_cast<__attribute__((address_space(3))) uint32_t*>(
      static_cast<uint32_t>(reinterpret_cast<uintptr_t>(l)));
  __builtin_amdgcn_global_load_lds(gp, lp, 16, 0, 0);
}

// ======================================================================
// gemm_bt: C[i,j] = sum_k A[i,k] * Bt[j,k]
// 256x256 tile, BK=64, 8 waves (512 thr, 2Mx4N -> 128x64 per wave),
// double-buffered LDS (128 KB), counted-vmcnt pipeline (never vmcnt(0)
// in steady state), 16x16x32 bf16 MFMA, XOR-seg swizzle (both sides).
// Ledger (per-thread gloads, 1 per 8KB chunk, 8 chunks per K-tile):
//   prologue: issue tile0 (8)
//   iter t: issue B(t+1) x4 ; vmcnt(4)  [tile t's 8 are oldest -> done]
//           barrier ; ds_read B(8)+A_lo(8) ; 32 MFMA ;
//           issue A(t+1) x4 ; ds_read A_hi(8) ; 32 MFMA ; barrier
// EPI 0: QKV   (bias; j<1024 -> qkT[i][j], else v[j-1024][i])
// EPI 1: scores (fp32 out, * scale)
// EPI 2: PV    (bf16 out, ld=512)
// EPI 3: proj  (fp32 out + proj_b[i] + resid)
// ======================================================================
template<int EPI>
__global__ __launch_bounds__(512, 2)
void gemm_bt(const bf16* __restrict__ A, int lda, long long sA,
             const bf16* __restrict__ Bt, int ldb, long long sB,
             char* __restrict__ Cp, long long sC,
             char* __restrict__ C2p, long long sC2,
             const float* __restrict__ bias,
             const float* __restrict__ resid,
             int K, float scale)
{
  __shared__ __align__(16) bf16 As[2 * 16384];   // 2 x [256][64]
  __shared__ __align__(16) bf16 Bs[2 * 16384];
  const int t = threadIdx.x;
  const int w = t >> 6;
  const int l = t & 63;
  const int z = blockIdx.z;
  A  += (long long)z * sA;
  Bt += (long long)z * sB;
  Cp += (long long)z * sC;
  if (C2p) C2p += (long long)z * sC2;
  const float* residb = (EPI == 3) ? (resid + (long long)z * CN) : nullptr;

  const int row0 = blockIdx.x * 256;
  const int col0 = blockIdx.y * 256;
  const int wr = w >> 2;              // 0..1 : wave row group (128 rows)
  const int wc = w & 3;               // 0..3 : wave col group (64 cols)

  f32x4 acc[8][4] = {};

  // ---- staging geometry: chunk = 64 rows x 64 cols bf16 = 8KB ----
  const int wv  = w;                  // wave id 0..7
  const int srow = (l >> 3);          // 0..7 row within wave's 8-row slice
  const int segp = ((l & 7) ^ srow) << 3;   // pre-swizzled k-seg (elements)
  const bf16* baseA = A  + (long long)(row0 + wv * 8 + srow) * lda + segp;
  const bf16* baseB = Bt + (long long)(col0 + wv * 8 + srow) * ldb + segp;

  auto stageA = [&](int kt1, int buf, int c) {
    gload_lds16(baseA + (long long)c * 64 * lda + kt1 * 64,
                &As[buf * 16384 + c * 4096 + wv * 512]);
  };
  auto stageB = [&](int kt1, int buf, int c) {
    gload_lds16(baseB + (long long)c * 64 * ldb + kt1 * 64,
                &Bs[buf * 16384 + c * 4096 + wv * 512]);
  };

  // ---- fragment-read geometry ----
  const int lrow = l & 15;
  const int lx = l & 7;
  const int s0 = (((l >> 4)) ^ lx) << 3;       // kk=0 swizzled seg offset
  const int s1 = (((l >> 4) + 4) ^ lx) << 3;   // kk=1

  const int nt = K >> 6;

  // prologue: tile 0 -> buf 0
  #pragma unroll
  for (int c = 0; c < 4; ++c) stageB(0, 0, c);
  #pragma unroll
  for (int c = 0; c < 4; ++c) stageA(0, 0, c);

  #pragma unroll 1
  for (int kt = 0; kt < nt; ++kt) {
    const int cur = kt & 1, nxt = cur ^ 1;
    const bool pf = (kt + 1) < nt;
    if (pf) {
      #pragma unroll
      for (int c = 0; c < 4; ++c) stageB(kt + 1, nxt, c);
      asm volatile("s_waitcnt vmcnt(4)" ::: "memory");
    } else {
      asm volatile("s_waitcnt vmcnt(0)" ::: "memory");
    }
    __builtin_amdgcn_sched_barrier(0);
    __builtin_amdgcn_s_barrier();
    asm volatile("" ::: "memory");

    const int ca = cur * 16384;
    bf16x8 bF0[4], bF1[4], aF0[4], aF1[4];
    #pragma unroll
    for (int nf = 0; nf < 4; ++nf) {
      const int r = wc * 64 + nf * 16 + lrow;
      bF0[nf] = *(const bf16x8*)&Bs[ca + r * 64 + s0];
      bF1[nf] = *(const bf16x8*)&Bs[ca + r * 64 + s1];
    }
    #pragma unroll
    for (int mf = 0; mf < 4; ++mf) {
      const int r = wr * 128 + mf * 16 + lrow;
      aF0[mf] = *(const bf16x8*)&As[ca + r * 64 + s0];
      aF1[mf] = *(const bf16x8*)&As[ca + r * 64 + s1];
    }
    __builtin_amdgcn_s_setprio(1);
    #pragma unroll
    for (int mf = 0; mf < 4; ++mf)
      #pragma unroll
      for (int nf = 0; nf < 4; ++nf)
        acc[mf][nf] = __builtin_amdgcn_mfma_f32_16x16x32_bf16(
            aF1[mf], bF1[nf],
            __builtin_amdgcn_mfma_f32_16x16x32_bf16(aF0[mf], bF0[nf], acc[mf][nf], 0, 0, 0),
            0, 0, 0);
    __builtin_amdgcn_s_setprio(0);
    if (pf) {
      #pragma unroll
      for (int c = 0; c < 4; ++c) stageA(kt + 1, nxt, c);
    }
    #pragma unroll
    for (int mf = 0; mf < 4; ++mf) {
      const int r = wr * 128 + 64 + mf * 16 + lrow;
      aF0[mf] = *(const bf16x8*)&As[ca + r * 64 + s0];
      aF1[mf] = *(const bf16x8*)&As[ca + r * 64 + s1];
    }
    __builtin_amdgcn_s_setprio(1);
    #pragma unroll
    for (int mf = 0; mf < 4; ++mf)
      #pragma unroll
      for (int nf = 0; nf < 4; ++nf)
        acc[4 + mf][nf] = __builtin_amdgcn_mfma_f32_16x16x32_bf16(
            aF1[mf], bF1[nf],
            __builtin_amdgcn_mfma_f32_16x16x32_bf16(aF0[mf], bF0[nf], acc[4 + mf][nf], 0, 0, 0),
            0, 0, 0);
    __builtin_amdgcn_s_setprio(0);
    asm volatile("" ::: "memory");
    __builtin_amdgcn_sched_barrier(0);
    __builtin_amdgcn_s_barrier();
  }

  (void)scale;
  const int ci = (l >> 4) * 4;
  const int cj = l & 15;
  #pragma unroll
  for (int mf = 0; mf < 8; ++mf) {
    const int i0 = row0 + wr * 128 + mf * 16 + ci;
    #pragma unroll
    for (int nf = 0; nf < 4; ++nf) {
      const int j = col0 + wc * 64 + nf * 16 + cj;
      const f32x4 a = acc[mf][nf];
      if constexpr (EPI == 0) {
        const float bj = bias[j];
        if (j < NPIX) {
          bf16* q = (bf16*)Cp;
          #pragma unroll
          for (int r = 0; r < 4; ++r)
            q[(i0 + r) * NPIX + j] = (bf16)(a[r] + bj);
        } else {
          bf16* vb = (bf16*)C2p;
          #pragma unroll
          for (int r = 0; r < 4; ++r)
            vb[(j - NPIX) * NPIX + (i0 + r)] = (bf16)(a[r] + bj);
        }
      } else if constexpr (EPI == 1) {
        float* sp = (float*)Cp;
        #pragma unroll
        for (int r = 0; r < 4; ++r)
          sp[(i0 + r) * NPIX + j] = a[r] * scale;
      } else if constexpr (EPI == 2) {
        bf16* hp = (bf16*)Cp;
        #pragma unroll
        for (int r = 0; r < 4; ++r)
          hp[(i0 + r) * CCH + j] = (bf16)a[r];
      } else {
        float* op = (float*)Cp;
        #pragma unroll
        for (int r = 0; r < 4; ++r)
          op[(i0 + r) * NPIX + j] = a[r] + bias[i0 + r] + residb[(i0 + r) * NPIX + j];
      }
    }
  }
}

// ---- fused GroupNorm: one block per (batch,group); 16ch x 1024px in LDS,
//      stats + normalize + transpose-write hnT[n][c] (bf16) in one pass ----
__global__ __launch_bounds__(256)
void gn_fused(const float* __restrict__ x, const float* __restrict__ gw,
              const float* __restrict__ gb, bf16* __restrict__ hnT)
{
  __shared__ float xs[16 * 1024];   // 64 KB
  __shared__ float red[8];
  const int b = blockIdx.x >> 5;
  const int g = blockIdx.x & 31;
  const float* xp = x + ((long long)b * CCH + g * 16) * NPIX;
  const int t = threadIdx.x;

  float4* xsv = (float4*)xs;
  const float4* gv = (const float4*)xp;
  float s = 0.f, ss = 0.f;
  #pragma unroll
  for (int i = 0; i < 16; ++i) {
    float4 v = gv[t + i * 256];
    xsv[t + i * 256] = v;
    s  += v.x + v.y + v.z + v.w;
    ss += v.x * v.x + v.y * v.y + v.z * v.z + v.w * v.w;
  }
  #pragma unroll
  for (int o = 32; o; o >>= 1) { s += __shfl_xor(s, o); ss += __shfl_xor(ss, o); }
  if ((t & 63) == 0) { red[t >> 6] = s; red[4 + (t >> 6)] = ss; }
  __syncthreads();
  s  = red[0] + red[1] + red[2] + red[3];
  ss = red[4] + red[5] + red[6] + red[7];
  const float mean = s * (1.f / 16384.f);
  const float var  = ss * (1.f / 16384.f) - mean * mean;
  const float rstd = rsqrtf(var + 1e-5f);

  float ac[16], bc[16];
  #pragma unroll
  for (int c = 0; c < 16; ++c) {
    const float wv = gw[g * 16 + c] * rstd;
    ac[c] = wv;
    bc[c] = gb[g * 16 + c] - mean * wv;
  }

  bf16* hp = hnT + (long long)b * CN + g * 16;
  #pragma unroll
  for (int r = 0; r < 4; ++r) {
    const int n = t + r * 256;
    bf16x8 o0, o1;
    #pragma unroll
    for (int c = 0; c < 8; ++c)
      o0[c] = (bf16)(xs[c * 1024 + n] * ac[c] + bc[c]);
    #pragma unroll
    for (int c = 0; c < 8; ++c)
      o1[c] = (bf16)(xs[(8 + c) * 1024 + n] * ac[8 + c] + bc[8 + c]);
    *(bf16x8*)&hp[(long long)n * CCH]     = o0;
    *(bf16x8*)&hp[(long long)n * CCH + 8] = o1;
  }
}

// ---- row softmax over 1024 fp32, write bf16 IN PLACE (row stride 4KB) ----
__global__ __launch_bounds__(256)
void softmax_rows(float* __restrict__ scores)
{
  float* p = scores + (long long)blockIdx.x * NPIX;
  const int t = threadIdx.x;
  const float4 v = ((const float4*)p)[t];
  float m = fmaxf(fmaxf(v.x, v.y), fmaxf(v.z, v.w));
  #pragma unroll
  for (int o = 32; o; o >>= 1) m = fmaxf(m, __shfl_xor(m, o));
  __shared__ float red[4];
  if ((t & 63) == 0) red[t >> 6] = m;
  __syncthreads();
  m = fmaxf(fmaxf(red[0], red[1]), fmaxf(red[2], red[3]));
  float4 e;
  e.x = __expf(v.x - m); e.y = __expf(v.y - m);
  e.z = __expf(v.z - m); e.w = __expf(v.w - m);
  float s = e.x + e.y + e.z + e.w;
  #pragma unroll
  for (int o = 32; o; o >>= 1) s += __shfl_xor(s, o);
  __syncthreads();
  if ((t & 63) == 0) red[t >> 6] = s;
  __syncthreads();
  s = red[0] + red[1] + red[2] + red[3];
  const float inv = 1.f / s;
  bf16x4 ov;
  ov[0] = (bf16)(e.x * inv); ov[1] = (bf16)(e.y * inv);
  ov[2] = (bf16)(e.z * inv); ov[3] = (bf16)(e.w * inv);
  *(bf16x4*)((bf16*)p + t * 4) = ov;
}

// ---- fp32 -> bf16 weight conversion (once) ----
__global__ __launch_bounds__(256)
void cvt_weights(const float* __restrict__ qw, const float* __restrict__ pw,
                 bf16* __restrict__ qwb, bf16* __restrict__ pwb)
{
  const int i = blockIdx.x * 256 + threadIdx.x;
  if (i < 3 * CCH * CCH) qwb[i] = (bf16)qw[i];
  if (i < CCH * CCH) pwb[i] = (bf16)pw[i];
}

extern "C" void kernel_launch(void* const* d_in, const int* in_sizes, int n_in,
                              void* d_out, int out_size, void* d_ws, size_t ws_size,
                              hipStream_t stream)
{
  const float* x      = (const float*)d_in[0];
  const float* gn_w   = (const float*)d_in[1];
  const float* gn_b   = (const float*)d_in[2];
  const float* qkv_w  = (const float*)d_in[3];
  const float* qkv_b  = (const float*)d_in[4];
  const float* proj_w = (const float*)d_in[5];
  const float* proj_b = (const float*)d_in[6];
  float* out = (float*)d_out;
  (void)in_sizes; (void)n_in; (void)out_size;

  char* ws = (char*)d_ws;
  size_t off = 0;
  auto alloc = [&](size_t bytes) -> char* {
    char* p = ws + off;
    off += (bytes + 255) & ~(size_t)255;
    return p;
  };
  bf16* qkv_wb  = (bf16*)alloc(3 * 512 * 512 * 2);
  bf16* proj_wb = (bf16*)alloc(512 * 512 * 2);
  const size_t fixed = off;
  // per-batch: hnT 1MB + qkT 2MB + v 1MB + scores 4MB + hvT 1MB
  const size_t per = 1048576ull + 2097152ull + 1048576ull + 4194304ull + 1048576ull;
  int Bc = 32;
  if (ws_size > fixed) {
    size_t fit = (ws_size - fixed) / per;
    if (fit < 32) Bc = (int)fit;
  } else {
    Bc = 0;
  }
  if (Bc < 1) Bc = 1;

  bf16*  hnT    = (bf16*) alloc((size_t)Bc * 1048576);
  bf16*  qkT    = (bf16*) alloc((size_t)Bc * 2097152);
  bf16*  vbuf   = (bf16*) alloc((size_t)Bc * 1048576);
  float* scores = (float*)alloc((size_t)Bc * 4194304);
  bf16*  hvT    = (bf16*) alloc((size_t)Bc * 1048576);

  cvt_weights<<<dim3(3072), 256, 0, stream>>>(qkv_w, proj_w, qkv_wb, proj_wb);

  const float scale = 0.044194173824159216f;  // 512^-0.5
  for (int b0 = 0; b0 < 32; b0 += Bc) {
    const int bc = (32 - b0 < Bc) ? (32 - b0) : Bc;
    const float* xb = x + (size_t)b0 * CN;

    gn_fused<<<dim3(bc * 32), 256, 0, stream>>>(xb, gn_w, gn_b, hnT);

    // QKV: [n][o] = hnT[n][c] . qkv_w[o][c];  q,k -> qkT[n][0..1023], v -> vbuf[c][m]
    gemm_bt<0><<<dim3(4, 6, bc), 512, 0, stream>>>(
        hnT, 512, 524288, qkv_wb, 512, 0,
        (char*)qkT, 2097152, (char*)vbuf, 1048576, qkv_b, nullptr, 512, 1.f);

    // scores[n][m] = q[n][:] . k[m][:]  (fp32, *scale)
    gemm_bt<1><<<dim3(4, 4, bc), 512, 0, stream>>>(
        qkT, 1024, 1048576, qkT + 512, 1024, 1048576,
        (char*)scores, 4194304, nullptr, 0, nullptr, nullptr, 512, scale);

    softmax_rows<<<dim3(bc * 1024), 256, 0, stream>>>(scores);

    // hvT[n][c] = attn[n][m] . v[c][m]   (attn bf16 in-place, lda=2048 elems)
    gemm_bt<2><<<dim3(4, 2, bc), 512, 0, stream>>>(
        (const bf16*)scores, 2048, 2097152, vbuf, 1024, 524288,
        (char*)hvT, 1048576, nullptr, 0, nullptr, nullptr, 1024, 1.f);

    // out[c][n] = proj_w[c][:] . hvT[n][:] + proj_b[c] + x[c][n]
    gemm_bt<3><<<dim3(2, 4, bc), 512, 0, stream>>>(
        proj_wb, 512, 0, hvT, 512, 524288,
        (char*)(out + (size_t)b0 * CN), 2097152, nullptr, 0, proj_b, xb, 512, 1.f);
  }
}